// Round 1
// baseline (2006.346 us; speedup 1.0000x reference)
//
#include <hip/hip_runtime.h>
#include <hip/hip_bf16.h>
#include <stdint.h>

// Problem dims
#define DIM_H 2048
#define DIM_I 8192
#define TOKENS 8192   // B*S = 4*2048

typedef __attribute__((ext_vector_type(8))) short bf16x8;
typedef __attribute__((ext_vector_type(4))) float f32x4;

__device__ __forceinline__ unsigned short f2bf(float f) {
    union { float f; unsigned u; } v; v.f = f;
    unsigned r = (v.u + 0x7FFF + ((v.u >> 16) & 1)) >> 16;
    return (unsigned short)r;
}

// ---------------- fp32 -> bf16 conversion (vectorized) ----------------
__global__ __launch_bounds__(256) void cvt_kernel(const float* __restrict__ in,
                                                  unsigned short* __restrict__ out,
                                                  int n4) {
    int stride = gridDim.x * blockDim.x;
    for (int j = blockIdx.x * blockDim.x + threadIdx.x; j < n4; j += stride) {
        float4 v = reinterpret_cast<const float4*>(in)[j];
        ushort4 o;
        o.x = f2bf(v.x); o.y = f2bf(v.y); o.z = f2bf(v.z); o.w = f2bf(v.w);
        reinterpret_cast<ushort4*>(out)[j] = o;
    }
}

// ---------------- GEMM1: P = silu(A@B1^T) * (A@B3^T), bf16 out ----------------
// A: [M][K] bf16 bits, B1/B3: [N][K] bf16 bits, P: [M][N] bf16 bits
// 128x128 tile, BK=32, 4 waves, each wave 64x64 (4x4 of 16x16x32 MFMA)
__global__ __launch_bounds__(256, 2) void gemm1_kernel(
    const unsigned short* __restrict__ A,
    const unsigned short* __restrict__ B1,
    const unsigned short* __restrict__ B3,
    unsigned short* __restrict__ P,
    int M, int N, int K)
{
    __shared__ __align__(16) unsigned short sA[128 * 32];
    __shared__ __align__(16) unsigned short sB1[128 * 32];
    __shared__ __align__(16) unsigned short sB3[128 * 32];

    const int t = threadIdx.x;
    const int lane = t & 63;
    const int wave = t >> 6;
    const int wr = wave >> 1, wc = wave & 1;
    const int bm0 = blockIdx.y * 128;
    const int bn0 = blockIdx.x * 128;

    f32x4 acc1[4][4] = {};
    f32x4 acc3[4][4] = {};

    // staging: thread t covers LDS elems [t*8, t*8+8) per issue (row t/4, col (t&3)*8)
    const int srow = t >> 2;
    const int scol = (t & 3) << 3;
    const unsigned short* ga  = A  + (size_t)(bm0 + srow) * K + scol;
    const unsigned short* gb1 = B1 + (size_t)(bn0 + srow) * K + scol;
    const unsigned short* gb3 = B3 + (size_t)(bn0 + srow) * K + scol;
    const int ldsbase = wave << 9;   // wave*512 elems = wave*1024 bytes

    const int frow = lane & 15;
    const int fk0  = (lane >> 4) << 3;

    for (int kt = 0; kt < K; kt += 32) {
        __syncthreads();
#define GLL(dst, src, it) \
        __builtin_amdgcn_global_load_lds( \
            (const __attribute__((address_space(1))) void*)((src) + (size_t)(it) * 64 * K + kt), \
            (__attribute__((address_space(3))) void*)&(dst)[(it) * 2048 + ldsbase], 16, 0, 0)
        GLL(sA,  ga,  0); GLL(sA,  ga,  1);
        GLL(sB1, gb1, 0); GLL(sB1, gb1, 1);
        GLL(sB3, gb3, 0); GLL(sB3, gb3, 1);
#undef GLL
        __syncthreads();

        bf16x8 af[4], b1f[4], b3f[4];
#pragma unroll
        for (int m = 0; m < 4; ++m)
            af[m] = *reinterpret_cast<const bf16x8*>(&sA[(wr * 64 + m * 16 + frow) * 32 + fk0]);
#pragma unroll
        for (int n = 0; n < 4; ++n) {
            b1f[n] = *reinterpret_cast<const bf16x8*>(&sB1[(wc * 64 + n * 16 + frow) * 32 + fk0]);
            b3f[n] = *reinterpret_cast<const bf16x8*>(&sB3[(wc * 64 + n * 16 + frow) * 32 + fk0]);
        }
#pragma unroll
        for (int m = 0; m < 4; ++m)
#pragma unroll
            for (int n = 0; n < 4; ++n) {
                acc1[m][n] = __builtin_amdgcn_mfma_f32_16x16x32_bf16(af[m], b1f[n], acc1[m][n], 0, 0, 0);
                acc3[m][n] = __builtin_amdgcn_mfma_f32_16x16x32_bf16(af[m], b3f[n], acc3[m][n], 0, 0, 0);
            }
    }

    const int crow0 = (lane >> 4) * 4;
    const int ccol  = lane & 15;
#pragma unroll
    for (int m = 0; m < 4; ++m) {
#pragma unroll
        for (int n = 0; n < 4; ++n) {
#pragma unroll
            for (int r = 0; r < 4; ++r) {
                float h1 = acc1[m][n][r];
                float h3 = acc3[m][n][r];
                float sig = 1.0f / (1.0f + __expf(-h1));
                float p = h1 * sig * h3;
                size_t row = (size_t)(bm0 + wr * 64 + m * 16 + crow0 + r);
                size_t col = (size_t)(bn0 + wc * 64 + n * 16 + ccol);
                P[row * (size_t)N + col] = f2bf(p);
            }
        }
    }
}

// ---------------- GEMM2: out = A@B^T, fp32 out, row-predicated by mask ----------------
__global__ __launch_bounds__(256, 2) void gemm2_kernel(
    const unsigned short* __restrict__ A,   // P [M][K]
    const unsigned short* __restrict__ B,   // [N][K]
    const int* __restrict__ mask,           // [M]
    float* __restrict__ out,                // [M][N]
    int M, int N, int K, int want)
{
    __shared__ __align__(16) unsigned short sA[128 * 32];
    __shared__ __align__(16) unsigned short sB[128 * 32];

    const int t = threadIdx.x;
    const int lane = t & 63;
    const int wave = t >> 6;
    const int wr = wave >> 1, wc = wave & 1;
    const int bm0 = blockIdx.y * 128;
    const int bn0 = blockIdx.x * 128;

    f32x4 acc[4][4] = {};

    const int srow = t >> 2;
    const int scol = (t & 3) << 3;
    const unsigned short* ga = A + (size_t)(bm0 + srow) * K + scol;
    const unsigned short* gb = B + (size_t)(bn0 + srow) * K + scol;
    const int ldsbase = wave << 9;

    const int frow = lane & 15;
    const int fk0  = (lane >> 4) << 3;

    for (int kt = 0; kt < K; kt += 32) {
        __syncthreads();
#define GLL(dst, src, it) \
        __builtin_amdgcn_global_load_lds( \
            (const __attribute__((address_space(1))) void*)((src) + (size_t)(it) * 64 * K + kt), \
            (__attribute__((address_space(3))) void*)&(dst)[(it) * 2048 + ldsbase], 16, 0, 0)
        GLL(sA, ga, 0); GLL(sA, ga, 1);
        GLL(sB, gb, 0); GLL(sB, gb, 1);
#undef GLL
        __syncthreads();

        bf16x8 af[4], bf[4];
#pragma unroll
        for (int m = 0; m < 4; ++m)
            af[m] = *reinterpret_cast<const bf16x8*>(&sA[(wr * 64 + m * 16 + frow) * 32 + fk0]);
#pragma unroll
        for (int n = 0; n < 4; ++n)
            bf[n] = *reinterpret_cast<const bf16x8*>(&sB[(wc * 64 + n * 16 + frow) * 32 + fk0]);
#pragma unroll
        for (int m = 0; m < 4; ++m)
#pragma unroll
            for (int n = 0; n < 4; ++n)
                acc[m][n] = __builtin_amdgcn_mfma_f32_16x16x32_bf16(af[m], bf[n], acc[m][n], 0, 0, 0);
    }

    const int crow0 = (lane >> 4) * 4;
    const int ccol  = lane & 15;
#pragma unroll
    for (int m = 0; m < 4; ++m) {
#pragma unroll
        for (int r = 0; r < 4; ++r) {
            int row = bm0 + wr * 64 + m * 16 + crow0 + r;
            bool en = (mask[row] != 0) == (want != 0);
            if (en) {
#pragma unroll
                for (int n = 0; n < 4; ++n) {
                    size_t col = (size_t)(bn0 + wc * 64 + n * 16 + ccol);
                    out[(size_t)row * (size_t)N + col] = acc[m][n][r];
                }
            }
        }
    }
}

extern "C" void kernel_launch(void* const* d_in, const int* in_sizes, int n_in,
                              void* d_out, int out_size, void* d_ws, size_t ws_size,
                              hipStream_t stream) {
    const float* x  = (const float*)d_in[0];
    const int*   mask = (const int*)d_in[1];
    const float* w1 = (const float*)d_in[2];
    const float* w2 = (const float*)d_in[3];
    const float* w3 = (const float*)d_in[4];
    const float* u1 = (const float*)d_in[5];
    const float* u2 = (const float*)d_in[6];
    const float* u3 = (const float*)d_in[7];
    float* out = (float*)d_out;

    const size_t XN = (size_t)TOKENS * DIM_H;   // 16.78M elems
    const size_t WN = (size_t)DIM_I * DIM_H;    // 16.78M elems
    const size_t PN = (size_t)TOKENS * DIM_I;   // 67.1M elems

    unsigned short* ws = (unsigned short*)d_ws;
    unsigned short* xb = ws;            // XN
    unsigned short* P  = xb + XN;       // PN
    unsigned short* bA = P + PN;        // WN (gate weight)
    unsigned short* bB = bA + WN;       // WN (up weight)
    unsigned short* bC = bB + WN;       // WN (down weight)

    const int cvtBlocks = 2048;
    const int n4 = (int)(WN / 4);

    // ---- branch w ----
    cvt_kernel<<<cvtBlocks, 256, 0, stream>>>(x,  xb, (int)(XN / 4));
    cvt_kernel<<<cvtBlocks, 256, 0, stream>>>(w1, bA, n4);
    cvt_kernel<<<cvtBlocks, 256, 0, stream>>>(w3, bB, n4);
    cvt_kernel<<<cvtBlocks, 256, 0, stream>>>(w2, bC, n4);

    gemm1_kernel<<<dim3(DIM_I / 128, TOKENS / 128), 256, 0, stream>>>(
        xb, bA, bB, P, TOKENS, DIM_I, DIM_H);
    gemm2_kernel<<<dim3(DIM_H / 128, TOKENS / 128), 256, 0, stream>>>(
        P, bC, mask, out, TOKENS, DIM_H, DIM_I, /*want=*/1);

    // ---- branch u (reuse weight slots + P) ----
    cvt_kernel<<<cvtBlocks, 256, 0, stream>>>(u1, bA, n4);
    cvt_kernel<<<cvtBlocks, 256, 0, stream>>>(u3, bB, n4);
    cvt_kernel<<<cvtBlocks, 256, 0, stream>>>(u2, bC, n4);

    gemm1_kernel<<<dim3(DIM_I / 128, TOKENS / 128), 256, 0, stream>>>(
        xb, bA, bB, P, TOKENS, DIM_I, DIM_H);
    gemm2_kernel<<<dim3(DIM_H / 128, TOKENS / 128), 256, 0, stream>>>(
        P, bC, mask, out, TOKENS, DIM_H, DIM_I, /*want=*/0);
}

// Round 2
// 1218.737 us; speedup vs baseline: 1.6462x; 1.6462x over previous
//
#include <hip/hip_runtime.h>
#include <hip/hip_bf16.h>
#include <stdint.h>

// Problem dims
#define DIM_H 2048
#define DIM_I 8192
#define TOKENS 8192   // B*S = 4*2048
#define RBMAX 66      // max 128-row blocks after per-branch padding (64 + 2)

typedef __attribute__((ext_vector_type(8))) short bf16x8;
typedef __attribute__((ext_vector_type(4))) float f32x4;

__device__ __forceinline__ unsigned short f2bf(float f) {
    union { float f; unsigned u; } v; v.f = f;
    unsigned r = (v.u + 0x7FFF + ((v.u >> 16) & 1)) >> 16;
    return (unsigned short)r;
}

// ---------------- fp32 -> bf16 conversion (vectorized) ----------------
__global__ __launch_bounds__(256) void cvt_kernel(const float* __restrict__ in,
                                                  unsigned short* __restrict__ out,
                                                  int n4) {
    int stride = gridDim.x * blockDim.x;
    for (int j = blockIdx.x * blockDim.x + threadIdx.x; j < n4; j += stride) {
        float4 v = reinterpret_cast<const float4*>(in)[j];
        ushort4 o;
        o.x = f2bf(v.x); o.y = f2bf(v.y); o.z = f2bf(v.z); o.w = f2bf(v.w);
        reinterpret_cast<ushort4*>(out)[j] = o;
    }
}

// ---------------- mask compaction: build row-index array + header ----------------
// idx[0..Mw)          = tokens with mask!=0 (in order)
// idx[MwP..MwP+Mu)    = tokens with mask==0 (in order), MwP = roundup(Mw,128)
// padding slots = -1.  hdr = {wBlocks, rbTotal, Mw, Mu}
__global__ __launch_bounds__(256) void compact_kernel(const int* __restrict__ mask,
                                                      int* __restrict__ idx,
                                                      int* __restrict__ hdr) {
    __shared__ int cnt[256];
    const int t = threadIdx.x;
    const int base = t * 32;
    unsigned bits = 0;
#pragma unroll
    for (int j = 0; j < 32; ++j)
        if (mask[base + j] != 0) bits |= (1u << j);
    const int c = __popc(bits);
    cnt[t] = c;
    __syncthreads();
    // inclusive scan (Hillis-Steele)
    for (int off = 1; off < 256; off <<= 1) {
        int v = cnt[t];
        int add = (t >= off) ? cnt[t - off] : 0;
        __syncthreads();
        cnt[t] = v + add;
        __syncthreads();
    }
    const int Mw  = cnt[255];
    const int MwP = (Mw + 127) & ~127;
    const int Mu  = TOKENS - Mw;
    const int MuP = (Mu + 127) & ~127;
    const int total = MwP + MuP;

    // pre-fill everything with -1 (padding marker)
    for (int j = t; j < RBMAX * 128; j += 256) idx[j] = -1;
    __syncthreads();

    int pw = cnt[t] - c;     // exclusive prefix of ones
    int pz = base - pw;      // exclusive prefix of zeros
#pragma unroll
    for (int j = 0; j < 32; ++j) {
        int tok = base + j;
        if ((bits >> j) & 1) idx[pw++] = tok;
        else                 idx[MwP + pz++] = tok;
    }
    if (t == 0) {
        hdr[0] = MwP >> 7;    // wBlocks
        hdr[1] = total >> 7;  // rbTotal
        hdr[2] = Mw;
        hdr[3] = Mu;
    }
}

// ---------------- GEMM1: P[c] = silu(x[idx[c]]@B1^T) * (x[idx[c]]@B3^T) ----------------
// Branch-w weights for row-blocks < wBlocks, branch-u otherwise.
// 128x128 tile, BK=32, 4 waves, each wave 64x64 (4x4 of 16x16x32 MFMA)
__global__ __launch_bounds__(256, 2) void gemm1_kernel(
    const unsigned short* __restrict__ xb,
    const unsigned short* __restrict__ w1b, const unsigned short* __restrict__ w3b,
    const unsigned short* __restrict__ u1b, const unsigned short* __restrict__ u3b,
    const int* __restrict__ idx, const int* __restrict__ hdr,
    unsigned short* __restrict__ P)
{
    const int wBlocks = hdr[0];
    const int rbTotal = hdr[1];
    const int rb = blockIdx.y;
    if (rb >= rbTotal) return;
    const bool isW = (rb < wBlocks);
    const unsigned short* B1 = isW ? w1b : u1b;
    const unsigned short* B3 = isW ? w3b : u3b;
    const int K = DIM_H, N = DIM_I;

    __shared__ __align__(16) unsigned short sA[128 * 32];
    __shared__ __align__(16) unsigned short sB1[128 * 32];
    __shared__ __align__(16) unsigned short sB3[128 * 32];

    const int t = threadIdx.x;
    const int lane = t & 63;
    const int wave = t >> 6;
    const int wr = wave >> 1, wc = wave & 1;
    const int bm0 = rb * 128;
    const int bn0 = blockIdx.x * 128;

    f32x4 acc1[4][4] = {};
    f32x4 acc3[4][4] = {};

    // staging: thread t covers LDS elems [t*8, t*8+8) per issue (row t/4, col (t&3)*8)
    const int srow = t >> 2;
    const int scol = (t & 3) << 3;
    int r0 = idx[bm0 + srow];       if (r0 < 0) r0 = 0;
    int r1 = idx[bm0 + srow + 64];  if (r1 < 0) r1 = 0;
    const unsigned short* ga0 = xb + (size_t)r0 * K + scol;
    const unsigned short* ga1 = xb + (size_t)r1 * K + scol;
    const unsigned short* gb1 = B1 + (size_t)(bn0 + srow) * K + scol;
    const unsigned short* gb3 = B3 + (size_t)(bn0 + srow) * K + scol;
    const int ldsbase = wave << 9;   // wave*512 elems

    const int frow = lane & 15;
    const int fk0  = (lane >> 4) << 3;

    for (int kt = 0; kt < K; kt += 32) {
        __syncthreads();
#define GLL1(dst, src, it) \
        __builtin_amdgcn_global_load_lds( \
            (const __attribute__((address_space(1))) void*)((src) + kt), \
            (__attribute__((address_space(3))) void*)&(dst)[(it) * 2048 + ldsbase], 16, 0, 0)
#define GLLB(dst, src, it) \
        __builtin_amdgcn_global_load_lds( \
            (const __attribute__((address_space(1))) void*)((src) + (size_t)(it) * 64 * K + kt), \
            (__attribute__((address_space(3))) void*)&(dst)[(it) * 2048 + ldsbase], 16, 0, 0)
        GLL1(sA, ga0, 0); GLL1(sA, ga1, 1);
        GLLB(sB1, gb1, 0); GLLB(sB1, gb1, 1);
        GLLB(sB3, gb3, 0); GLLB(sB3, gb3, 1);
#undef GLL1
#undef GLLB
        __syncthreads();

        bf16x8 af[4], b1f[4], b3f[4];
#pragma unroll
        for (int m = 0; m < 4; ++m)
            af[m] = *reinterpret_cast<const bf16x8*>(&sA[(wr * 64 + m * 16 + frow) * 32 + fk0]);
#pragma unroll
        for (int n = 0; n < 4; ++n) {
            b1f[n] = *reinterpret_cast<const bf16x8*>(&sB1[(wc * 64 + n * 16 + frow) * 32 + fk0]);
            b3f[n] = *reinterpret_cast<const bf16x8*>(&sB3[(wc * 64 + n * 16 + frow) * 32 + fk0]);
        }
#pragma unroll
        for (int m = 0; m < 4; ++m)
#pragma unroll
            for (int n = 0; n < 4; ++n) {
                acc1[m][n] = __builtin_amdgcn_mfma_f32_16x16x32_bf16(af[m], b1f[n], acc1[m][n], 0, 0, 0);
                acc3[m][n] = __builtin_amdgcn_mfma_f32_16x16x32_bf16(af[m], b3f[n], acc3[m][n], 0, 0, 0);
            }
    }

    const int crow0 = (lane >> 4) * 4;
    const int ccol  = lane & 15;
#pragma unroll
    for (int m = 0; m < 4; ++m) {
#pragma unroll
        for (int n = 0; n < 4; ++n) {
#pragma unroll
            for (int r = 0; r < 4; ++r) {
                float h1 = acc1[m][n][r];
                float h3 = acc3[m][n][r];
                float sig = 1.0f / (1.0f + __expf(-h1));
                float p = h1 * sig * h3;
                size_t row = (size_t)(bm0 + wr * 64 + m * 16 + crow0 + r);
                size_t col = (size_t)(bn0 + wc * 64 + n * 16 + ccol);
                P[row * (size_t)N + col] = f2bf(p);
            }
        }
    }
}

// ---------------- GEMM2: out[idx[c]] = P[c] @ B^T (scatter, padding suppressed) ----------------
__global__ __launch_bounds__(256, 2) void gemm2_kernel(
    const unsigned short* __restrict__ P,
    const unsigned short* __restrict__ w2b, const unsigned short* __restrict__ u2b,
    const int* __restrict__ idx, const int* __restrict__ hdr,
    float* __restrict__ out)
{
    const int wBlocks = hdr[0];
    const int rbTotal = hdr[1];
    const int rb = blockIdx.y;
    if (rb >= rbTotal) return;
    const unsigned short* B = (rb < wBlocks) ? w2b : u2b;
    const int K = DIM_I, N = DIM_H;

    __shared__ __align__(16) unsigned short sA[128 * 32];
    __shared__ __align__(16) unsigned short sB[128 * 32];

    const int t = threadIdx.x;
    const int lane = t & 63;
    const int wave = t >> 6;
    const int wr = wave >> 1, wc = wave & 1;
    const int bm0 = rb * 128;
    const int bn0 = blockIdx.x * 128;

    f32x4 acc[4][4] = {};

    const int srow = t >> 2;
    const int scol = (t & 3) << 3;
    const unsigned short* ga = P + (size_t)(bm0 + srow) * K + scol;
    const unsigned short* gb = B + (size_t)(bn0 + srow) * K + scol;
    const int ldsbase = wave << 9;

    const int frow = lane & 15;
    const int fk0  = (lane >> 4) << 3;

    for (int kt = 0; kt < K; kt += 32) {
        __syncthreads();
#define GLL(dst, src, it) \
        __builtin_amdgcn_global_load_lds( \
            (const __attribute__((address_space(1))) void*)((src) + (size_t)(it) * 64 * K + kt), \
            (__attribute__((address_space(3))) void*)&(dst)[(it) * 2048 + ldsbase], 16, 0, 0)
        GLL(sA, ga, 0); GLL(sA, ga, 1);
        GLL(sB, gb, 0); GLL(sB, gb, 1);
#undef GLL
        __syncthreads();

        bf16x8 af[4], bf[4];
#pragma unroll
        for (int m = 0; m < 4; ++m)
            af[m] = *reinterpret_cast<const bf16x8*>(&sA[(wr * 64 + m * 16 + frow) * 32 + fk0]);
#pragma unroll
        for (int n = 0; n < 4; ++n)
            bf[n] = *reinterpret_cast<const bf16x8*>(&sB[(wc * 64 + n * 16 + frow) * 32 + fk0]);
#pragma unroll
        for (int m = 0; m < 4; ++m)
#pragma unroll
            for (int n = 0; n < 4; ++n)
                acc[m][n] = __builtin_amdgcn_mfma_f32_16x16x32_bf16(af[m], bf[n], acc[m][n], 0, 0, 0);
    }

    const int crow0 = (lane >> 4) * 4;
    const int ccol  = lane & 15;
#pragma unroll
    for (int m = 0; m < 4; ++m) {
#pragma unroll
        for (int r = 0; r < 4; ++r) {
            int rowc = bm0 + wr * 64 + m * 16 + crow0 + r;
            int g = idx[rowc];
            if (g >= 0) {
#pragma unroll
                for (int n = 0; n < 4; ++n) {
                    size_t col = (size_t)(bn0 + wc * 64 + n * 16 + ccol);
                    out[(size_t)g * (size_t)N + col] = acc[m][n][r];
                }
            }
        }
    }
}

extern "C" void kernel_launch(void* const* d_in, const int* in_sizes, int n_in,
                              void* d_out, int out_size, void* d_ws, size_t ws_size,
                              hipStream_t stream) {
    const float* x    = (const float*)d_in[0];
    const int*   mask = (const int*)d_in[1];
    const float* w1 = (const float*)d_in[2];
    const float* w2 = (const float*)d_in[3];
    const float* w3 = (const float*)d_in[4];
    const float* u1 = (const float*)d_in[5];
    const float* u2 = (const float*)d_in[6];
    const float* u3 = (const float*)d_in[7];
    float* out = (float*)d_out;

    const size_t XN = (size_t)TOKENS * DIM_H;       // 16.78M elems
    const size_t WN = (size_t)DIM_I * DIM_H;        // 16.78M elems
    const size_t PN = (size_t)(RBMAX * 128) * DIM_I; // 69.2M elems (compacted rows, padded)

    unsigned short* ws = (unsigned short*)d_ws;
    unsigned short* xb = ws;            // XN
    unsigned short* P  = xb + XN;       // PN
    unsigned short* s0 = P + PN;        // WN
    unsigned short* s1 = s0 + WN;       // WN
    unsigned short* s2 = s1 + WN;       // WN
    unsigned short* s3 = s2 + WN;       // WN
    int* idx = (int*)(s3 + WN);         // RBMAX*128 ints
    int* hdr = idx + RBMAX * 128;       // 8 ints

    const int cvtBlocks = 2048;
    const int n4 = (int)(WN / 4);

    // conversions + compaction
    cvt_kernel<<<cvtBlocks, 256, 0, stream>>>(x,  xb, (int)(XN / 4));
    cvt_kernel<<<cvtBlocks, 256, 0, stream>>>(w1, s0, n4);
    cvt_kernel<<<cvtBlocks, 256, 0, stream>>>(w3, s1, n4);
    cvt_kernel<<<cvtBlocks, 256, 0, stream>>>(u1, s2, n4);
    cvt_kernel<<<cvtBlocks, 256, 0, stream>>>(u3, s3, n4);
    compact_kernel<<<1, 256, 0, stream>>>(mask, idx, hdr);

    // fused dual-branch GEMM1 over compacted rows
    gemm1_kernel<<<dim3(DIM_I / 128, RBMAX), 256, 0, stream>>>(
        xb, s0, s1, s2, s3, idx, hdr, P);

    // down-proj weights reuse slots s0/s1
    cvt_kernel<<<cvtBlocks, 256, 0, stream>>>(w2, s0, n4);
    cvt_kernel<<<cvtBlocks, 256, 0, stream>>>(u2, s1, n4);

    // GEMM2 + scatter
    gemm2_kernel<<<dim3(DIM_H / 128, RBMAX), 256, 0, stream>>>(
        P, s0, s1, idx, hdr, out);
}

// Round 3
// 1086.528 us; speedup vs baseline: 1.8466x; 1.1217x over previous
//
#include <hip/hip_runtime.h>
#include <hip/hip_bf16.h>
#include <stdint.h>

#define DIM_H 2048
#define DIM_I 8192
#define TOKENS 8192
#define RB256 34            // max 256-row compacted blocks (32 + 2 pad)
#define CROWS (RB256*256)   // 8704

typedef __attribute__((ext_vector_type(8))) short bf16x8;
typedef __attribute__((ext_vector_type(4))) float f32x4;

#define MF(a,b,c) __builtin_amdgcn_mfma_f32_16x16x32_bf16((a),(b),(c),0,0,0)

__device__ __forceinline__ unsigned short f2bf(float f) {
    union { float f; unsigned u; } v; v.f = f;
    return (unsigned short)((v.u + 0x7FFF + ((v.u >> 16) & 1)) >> 16);
}

// ---------------- fp32 -> bf16 conversion ----------------
__global__ __launch_bounds__(256) void cvt_kernel(const float* __restrict__ in,
                                                  unsigned short* __restrict__ out,
                                                  int n4) {
    int stride = gridDim.x * blockDim.x;
    for (int j = blockIdx.x * blockDim.x + threadIdx.x; j < n4; j += stride) {
        float4 v = reinterpret_cast<const float4*>(in)[j];
        ushort4 o;
        o.x = f2bf(v.x); o.y = f2bf(v.y); o.z = f2bf(v.z); o.w = f2bf(v.w);
        reinterpret_cast<ushort4*>(out)[j] = o;
    }
}

// interleave gate/up weights: W13[32g + j] = w1[16g + j]; W13[32g + 16 + j] = w3[16g + j]
__global__ __launch_bounds__(256) void cvt13_kernel(const float* __restrict__ w1,
                                                    const float* __restrict__ w3,
                                                    unsigned short* __restrict__ W13,
                                                    int n4) {
    int stride = gridDim.x * blockDim.x;
    for (int j = blockIdx.x * blockDim.x + threadIdx.x; j < n4; j += stride) {
        int flat = j << 2;
        int R = flat >> 11;          // row (DIM_H = 2048 cols)
        int col = flat & 2047;
        int orow = ((R >> 4) << 5) | (R & 15);
        float4 v1 = reinterpret_cast<const float4*>(w1)[j];
        float4 v3 = reinterpret_cast<const float4*>(w3)[j];
        ushort4 o1, o3;
        o1.x=f2bf(v1.x); o1.y=f2bf(v1.y); o1.z=f2bf(v1.z); o1.w=f2bf(v1.w);
        o3.x=f2bf(v3.x); o3.y=f2bf(v3.y); o3.z=f2bf(v3.z); o3.w=f2bf(v3.w);
        *reinterpret_cast<ushort4*>(&W13[(size_t)orow * DIM_H + col]) = o1;
        *reinterpret_cast<ushort4*>(&W13[(size_t)(orow + 16) * DIM_H + col]) = o3;
    }
}

// ---------------- mask compaction (256-row padding) ----------------
__global__ __launch_bounds__(256) void compact_kernel(const int* __restrict__ mask,
                                                      int* __restrict__ idx,
                                                      int* __restrict__ hdr) {
    __shared__ int cnt[256];
    const int t = threadIdx.x;
    const int base = t * 32;
    unsigned bits = 0;
#pragma unroll
    for (int j = 0; j < 32; ++j)
        if (mask[base + j] != 0) bits |= (1u << j);
    const int c = __popc(bits);
    cnt[t] = c;
    __syncthreads();
    for (int off = 1; off < 256; off <<= 1) {
        int v = cnt[t];
        int add = (t >= off) ? cnt[t - off] : 0;
        __syncthreads();
        cnt[t] = v + add;
        __syncthreads();
    }
    const int Mw  = cnt[255];
    const int MwP = (Mw + 255) & ~255;
    const int Mu  = TOKENS - Mw;
    const int MuP = (Mu + 255) & ~255;

    for (int j = t; j < CROWS; j += 256) idx[j] = -1;
    __syncthreads();

    int pw = cnt[t] - c;
    int pz = base - pw;
#pragma unroll
    for (int j = 0; j < 32; ++j) {
        int tok = base + j;
        if ((bits >> j) & 1) idx[pw++] = tok;
        else                 idx[MwP + pz++] = tok;
    }
    if (t == 0) {
        hdr[0] = MwP >> 8;           // w-blocks (256-row units)
        hdr[1] = (MwP + MuP) >> 8;   // total blocks
        hdr[2] = Mw;
        hdr[3] = Mu;
    }
}

// ================= 256x256 / BK=64 / 8-wave 8-phase GEMM machinery =================
// LDS: 2 buffers x { A[k0], A[k1], B[k0], B[k1] }, each slice = 256 rows x 32 cols bf16 (16KB)
// slice swizzle (16B units): phys c' = c16 ^ ((row>>1)&3)  (involution; applied on global src + ds_read)

#define LDA4(BASE, KS, MQ) do { \
    const unsigned short* _sl = &smem[(BASE) + (KS)*8192]; \
    af0 = *reinterpret_cast<const bf16x8*>(&_sl[(rAb + (MQ)*64 +  0)*32 + c16r]); \
    af1 = *reinterpret_cast<const bf16x8*>(&_sl[(rAb + (MQ)*64 + 16)*32 + c16r]); \
    af2 = *reinterpret_cast<const bf16x8*>(&_sl[(rAb + (MQ)*64 + 32)*32 + c16r]); \
    af3 = *reinterpret_cast<const bf16x8*>(&_sl[(rAb + (MQ)*64 + 48)*32 + c16r]); \
} while(0)

#define LDB4(BASE, KS) do { \
    const unsigned short* _sl = &smem[(BASE) + 16384 + (KS)*8192]; \
    bfr0 = *reinterpret_cast<const bf16x8*>(&_sl[(rBb +  0)*32 + c16r]); \
    bfr1 = *reinterpret_cast<const bf16x8*>(&_sl[(rBb + 16)*32 + c16r]); \
    bfr2 = *reinterpret_cast<const bf16x8*>(&_sl[(rBb + 32)*32 + c16r]); \
    bfr3 = *reinterpret_cast<const bf16x8*>(&_sl[(rBb + 48)*32 + c16r]); \
} while(0)

#define STAGE2(UB_, S0_, S1_, KOFS_) do { \
    __builtin_amdgcn_global_load_lds((const __attribute__((address_space(1))) void*)((S0_) + (KOFS_)), \
        (__attribute__((address_space(3))) void*)&smem[(UB_) + wave*512], 16, 0, 0); \
    __builtin_amdgcn_global_load_lds((const __attribute__((address_space(1))) void*)((S1_) + (KOFS_)), \
        (__attribute__((address_space(3))) void*)&smem[(UB_) + 4096 + wave*512], 16, 0, 0); \
} while(0)

#define MFMA16(M0) do { \
    acc[M0+0][0]=MF(af0,bfr0,acc[M0+0][0]); acc[M0+0][1]=MF(af0,bfr1,acc[M0+0][1]); \
    acc[M0+0][2]=MF(af0,bfr2,acc[M0+0][2]); acc[M0+0][3]=MF(af0,bfr3,acc[M0+0][3]); \
    acc[M0+1][0]=MF(af1,bfr0,acc[M0+1][0]); acc[M0+1][1]=MF(af1,bfr1,acc[M0+1][1]); \
    acc[M0+1][2]=MF(af1,bfr2,acc[M0+1][2]); acc[M0+1][3]=MF(af1,bfr3,acc[M0+1][3]); \
    acc[M0+2][0]=MF(af2,bfr0,acc[M0+2][0]); acc[M0+2][1]=MF(af2,bfr1,acc[M0+2][1]); \
    acc[M0+2][2]=MF(af2,bfr2,acc[M0+2][2]); acc[M0+2][3]=MF(af2,bfr3,acc[M0+2][3]); \
    acc[M0+3][0]=MF(af3,bfr0,acc[M0+3][0]); acc[M0+3][1]=MF(af3,bfr1,acc[M0+3][1]); \
    acc[M0+3][2]=MF(af3,bfr2,acc[M0+3][2]); acc[M0+3][3]=MF(af3,bfr3,acc[M0+3][3]); \
} while(0)

#define BARMFMA(M0) do { \
    __builtin_amdgcn_s_barrier(); \
    asm volatile("s_waitcnt lgkmcnt(0)" ::: "memory"); \
    __builtin_amdgcn_sched_barrier(0); \
    __builtin_amdgcn_s_setprio(1); \
    MFMA16(M0); \
    __builtin_amdgcn_s_setprio(0); \
    __builtin_amdgcn_s_barrier(); \
} while(0)

// phases per K-tile: P1 (k0, m 0-3), P2 (k0, m 4-7), P3 (k1, m 0-3), P4 (k1, m 4-7)
// stage: P1->A[t+1,k1](nxt), P2->B[t+1,k1](nxt), P3->A[t+2,k0](cur), P4->B[t+2,k0](cur) + vmcnt(4)
#define KLOOP(NT) do { \
    STAGE2(0,             sa0, sa1, 0);   STAGE2(16384,         sb0, sb1, 0); \
    STAGE2(8192,          sa0, sa1, 32);  STAGE2(16384 + 8192,  sb0, sb1, 32); \
    STAGE2(32768,         sa0, sa1, 64);  STAGE2(32768 + 16384, sb0, sb1, 64); \
    asm volatile("s_waitcnt vmcnt(4)" ::: "memory"); \
    __builtin_amdgcn_s_barrier(); \
    for (int t = 0; t < (NT); ++t) { \
        const int cur = (t & 1) << 15; \
        const int nxt = cur ^ 32768; \
        const int k1o = ((t + 1 < (NT)) ? t + 1 : t) * 64 + 32; \
        const int k2o = ((t + 2 < (NT)) ? t + 2 : t) * 64; \
        LDA4(cur, 0, 0); LDB4(cur, 0); STAGE2(nxt + 8192,  sa0, sa1, k1o); BARMFMA(0); \
        LDA4(cur, 0, 1);               STAGE2(nxt + 24576, sb0, sb1, k1o); BARMFMA(4); \
        LDA4(cur, 1, 0); LDB4(cur, 1); STAGE2(cur,         sa0, sa1, k2o); BARMFMA(0); \
        LDA4(cur, 1, 1);               STAGE2(cur + 16384, sb0, sb1, k2o); \
        asm volatile("s_waitcnt vmcnt(4)" ::: "memory"); \
        BARMFMA(4); \
    } \
} while(0)

// ---------------- GEMM1: P = silu(x@w1^T) * (x@w3^T), gathered rows, dual-branch ----------------
__global__ __launch_bounds__(512, 2) void gemm1_kernel(
    const unsigned short* __restrict__ xb,
    const unsigned short* __restrict__ W13,
    const unsigned short* __restrict__ U13,
    const int* __restrict__ idx, const int* __restrict__ hdr,
    unsigned short* __restrict__ P)
{
    __shared__ __align__(16) unsigned short smem[65536];  // 128 KB
    const int wB  = hdr[0];
    const int rbT = hdr[1];
    const int nwg = gridDim.x;                 // 64*RB256, divisible by 8
    const int q8  = nwg >> 3;
    const int swz = ((int)blockIdx.x & 7) * q8 + ((int)blockIdx.x >> 3);
    const int bx = swz & 63;                   // N-tile (64 tiles of 256 W13-rows)
    const int rb = swz >> 6;                   // M-block
    if (rb >= rbT) return;
    const unsigned short* Bm = (rb < wB) ? W13 : U13;
    const int bm0 = rb << 8;
    const int bn0 = bx << 8;

    const int tid  = threadIdx.x;
    const int lane = tid & 63;
    const int wave = tid >> 6;
    const int wrM = wave >> 2;
    const int wcN = wave & 3;
    const int rAb = wrM * 128 + (lane & 15);
    const int rBb = wcN * 64 + (lane & 15);
    const int c16r = (((lane >> 4) ^ ((lane >> 1) & 3))) << 3;

    const int p0 = tid, p1 = 512 + tid;
    const int r0 = p0 >> 2, r1 = p1 >> 2;
    const int c0 = ((p0 & 3) ^ ((r0 >> 1) & 3)) << 3;
    const int c1 = ((p1 & 3) ^ ((r1 >> 1) & 3)) << 3;
    int t0 = idx[bm0 + r0]; if (t0 < 0) t0 = 0;
    int t1 = idx[bm0 + r1]; if (t1 < 0) t1 = 0;
    const unsigned short* sa0 = xb + (size_t)t0 * DIM_H + c0;
    const unsigned short* sa1 = xb + (size_t)t1 * DIM_H + c1;
    const unsigned short* sb0 = Bm + (size_t)(bn0 + r0) * DIM_H + c0;
    const unsigned short* sb1 = Bm + (size_t)(bn0 + r1) * DIM_H + c1;

    f32x4 acc[8][4] = {};
    bf16x8 af0, af1, af2, af3, bfr0, bfr1, bfr2, bfr3;

    KLOOP(32);   // K = 2048

    // epilogue: n-frag pairs (2q, 2q+1) = (h1, h3) for the same 16 P-cols
    const int crow = (lane >> 4) << 2;
    const int ccol = lane & 15;
    unsigned short* Pw = P + (size_t)(bm0 + wrM * 128) * DIM_I
                           + (size_t)bx * 128 + wcN * 32 + ccol;
#pragma unroll
    for (int m = 0; m < 8; ++m) {
#pragma unroll
        for (int q = 0; q < 2; ++q) {
            f32x4 h1 = acc[m][2 * q];
            f32x4 h3 = acc[m][2 * q + 1];
#pragma unroll
            for (int r = 0; r < 4; ++r) {
                float a = h1[r];
                float p = a * (1.0f / (1.0f + __expf(-a))) * h3[r];
                Pw[(size_t)(m * 16 + crow + r) * DIM_I + q * 16] = f2bf(p);
            }
        }
    }
}

// ---------------- GEMM2: out[idx[c]] = P[c] @ w2^T (scatter) ----------------
__global__ __launch_bounds__(512, 2) void gemm2_kernel(
    const unsigned short* __restrict__ P,
    const unsigned short* __restrict__ w2b, const unsigned short* __restrict__ u2b,
    const int* __restrict__ idx, const int* __restrict__ hdr,
    float* __restrict__ out)
{
    __shared__ __align__(16) unsigned short smem[65536];
    const int wB  = hdr[0];
    const int rbT = hdr[1];
    const int nwg = gridDim.x;                 // 8*RB256, divisible by 8
    const int q8  = nwg >> 3;
    const int swz = ((int)blockIdx.x & 7) * q8 + ((int)blockIdx.x >> 3);
    const int bx = swz & 7;                    // N-tile (8 tiles of 256 H-cols)
    const int rb = swz >> 3;
    if (rb >= rbT) return;
    const unsigned short* Bm = (rb < wB) ? w2b : u2b;
    const int bm0 = rb << 8;
    const int bn0 = bx << 8;

    const int tid  = threadIdx.x;
    const int lane = tid & 63;
    const int wave = tid >> 6;
    const int wrM = wave >> 2;
    const int wcN = wave & 3;
    const int rAb = wrM * 128 + (lane & 15);
    const int rBb = wcN * 64 + (lane & 15);
    const int c16r = (((lane >> 4) ^ ((lane >> 1) & 3))) << 3;

    const int p0 = tid, p1 = 512 + tid;
    const int r0 = p0 >> 2, r1 = p1 >> 2;
    const int c0 = ((p0 & 3) ^ ((r0 >> 1) & 3)) << 3;
    const int c1 = ((p1 & 3) ^ ((r1 >> 1) & 3)) << 3;
    const unsigned short* sa0 = P  + (size_t)(bm0 + r0) * DIM_I + c0;
    const unsigned short* sa1 = P  + (size_t)(bm0 + r1) * DIM_I + c1;
    const unsigned short* sb0 = Bm + (size_t)(bn0 + r0) * DIM_I + c0;
    const unsigned short* sb1 = Bm + (size_t)(bn0 + r1) * DIM_I + c1;

    f32x4 acc[8][4] = {};
    bf16x8 af0, af1, af2, af3, bfr0, bfr1, bfr2, bfr3;

    KLOOP(128);  // K = 8192

    const int crow = (lane >> 4) << 2;
    const int ccol = lane & 15;
#pragma unroll
    for (int m = 0; m < 8; ++m) {
#pragma unroll
        for (int r = 0; r < 4; ++r) {
            int rowc = bm0 + wrM * 128 + m * 16 + crow + r;
            int g = idx[rowc];
            if (g >= 0) {
                float* op = out + (size_t)g * DIM_H + bn0 + wcN * 64 + ccol;
#pragma unroll
                for (int n = 0; n < 4; ++n) op[n * 16] = acc[m][n][r];
            }
        }
    }
}

extern "C" void kernel_launch(void* const* d_in, const int* in_sizes, int n_in,
                              void* d_out, int out_size, void* d_ws, size_t ws_size,
                              hipStream_t stream) {
    const float* x    = (const float*)d_in[0];
    const int*   mask = (const int*)d_in[1];
    const float* w1 = (const float*)d_in[2];
    const float* w2 = (const float*)d_in[3];
    const float* w3 = (const float*)d_in[4];
    const float* u1 = (const float*)d_in[5];
    const float* u2 = (const float*)d_in[6];
    const float* u3 = (const float*)d_in[7];
    float* out = (float*)d_out;

    const size_t XN   = (size_t)TOKENS * DIM_H;      // 16.78M
    const size_t WN   = (size_t)DIM_I * DIM_H;       // 16.78M
    const size_t PN   = (size_t)CROWS * DIM_I;       // 71.3M
    const size_t W13N = 2 * WN;                      // 33.55M

    unsigned short* ws  = (unsigned short*)d_ws;
    unsigned short* xb  = ws;                        // XN
    unsigned short* Pb  = xb + XN;                   // PN
    unsigned short* W13 = Pb + PN;                   // W13N
    unsigned short* U13 = W13 + W13N;                // W13N
    int* idx = (int*)(U13 + W13N);                   // CROWS ints
    int* hdr = idx + CROWS;                          // 8 ints
    // after gemm1, W13/U13 space is reused for the (smaller) down-proj weights
    unsigned short* w2b = W13;
    unsigned short* u2b = U13;

    const int cvtBlocks = 2048;
    const int n4 = (int)(WN / 4);

    cvt_kernel  <<<cvtBlocks, 256, 0, stream>>>(x, xb, (int)(XN / 4));
    cvt13_kernel<<<cvtBlocks, 256, 0, stream>>>(w1, w3, W13, n4);
    cvt13_kernel<<<cvtBlocks, 256, 0, stream>>>(u1, u3, U13, n4);
    compact_kernel<<<1, 256, 0, stream>>>(mask, idx, hdr);

    gemm1_kernel<<<64 * RB256, 512, 0, stream>>>(xb, W13, U13, idx, hdr, Pb);

    cvt_kernel<<<cvtBlocks, 256, 0, stream>>>(w2, w2b, n4);
    cvt_kernel<<<cvtBlocks, 256, 0, stream>>>(u2, u2b, n4);

    gemm2_kernel<<<8 * RB256, 512, 0, stream>>>(Pb, w2b, u2b, idx, hdr, out);
}